// Round 4
// baseline (242.717 us; speedup 1.0000x reference)
//
#include <hip/hip_runtime.h>

// VectorQuantizer on MI355X (gfx950) — round 6: 2 blocks/CU phase overlap
// x: [262144, 64] fp32; embeddings: [64, 512] fp32 (codes are COLUMNS)
// out: quantized [N*64] fp32 ++ loss scalar
//
// sim = x.e computed as xh.eh + xl.eh + xh.el (bf16 split, abs err ~3e-5)
// score = sim - 0.5*||e||^2  (accumulator-initialized; argmax == argmin dist)
//
// Round-6 changes vs round-5 (115 us, all pipes <31% busy):
//   Diagnosis: 130 KB LDS pinned ONE block per CU -> that block's memory
//   phases (x-load prologue, gather/write epilogue) and compute phase
//   (t-loop on LDS table) SERIALIZE per CU; no co-resident block fills the
//   complementary pipe. dur ~= sum of phases, every pipe idle >=70%.
//   1. LDS table halved: eh (64KB) + norms (2KB) stay in LDS; el read from
//      global (32 KB table, L2-hot; r2->r3 showed global ~= LDS for this).
//      66 KB -> 2 blocks/CU co-resident -> phases overlap across blocks.
//   2. 512-thread blocks, 256 rows each -> 1024 blocks (balance slack; and
//      16 waves/CU legal VGPR cap 128 — escapes the 64-reg jail of the
//      1024-thread shape: r3/r5 proved the allocator pins those at 64).
//   3. 6-deep serial MFMA accumulator chain split into 3 independent 2-deep
//      chains (accA=eh.xh(+cn), accB=el.xh, accC=eh.xl; s=A+B+C) -> 3x ILP
//      in the compute phase for +8 VALU adds/iter.
// near-tie (gap < 1e-3): whole-wave cooperative exact fp64 rescan (rare)

#define NVEC 262144
#define DDIM 64
#define KCB  512
#define TIE_TH 1e-3f

// ws layout (4-byte units)
#define WS_LOSS  0
#define WS_CNORM 64                      // 512 floats
#define WS_ET    1024                    // 512*64 floats (code-major codebook)
#define WS_EH    (WS_ET + KCB * DDIM)    // 32 tiles * 2 chunks * 64 lanes * 16B
#define WS_EL    (WS_EH + 32 * 2 * 64 * 4)
#define WS_END   (WS_EL + 32 * 2 * 64 * 4)

typedef __attribute__((ext_vector_type(8))) short bf16x8;
typedef __attribute__((ext_vector_type(4))) float f32x4;

static __device__ __forceinline__ unsigned short f2bf_rne(float f) {
    unsigned u = __float_as_uint(f);
    unsigned r = (u + 0x7FFFu + ((u >> 16) & 1u)) >> 16;
    return (unsigned short)r;
}
static __device__ __forceinline__ float bf2f(unsigned short h) {
    return __uint_as_float(((unsigned)h) << 16);
}

// ---------------- prep 1: et (code-major fp32), cnorm, zero loss ----------------
__global__ __launch_bounds__(512) void vq_prep1(const float* __restrict__ emb,
                                                float* __restrict__ wsf) {
    int k = threadIdx.x;
    float s = 0.f;
    float* et = wsf + WS_ET;
    #pragma unroll
    for (int d = 0; d < DDIM; ++d) {
        float e = emb[d * KCB + k];
        s += e * e;
        et[k * DDIM + d] = e;
    }
    wsf[WS_CNORM + k] = s;
    if (k == 0) wsf[WS_LOSS] = 0.f;
}

// ---------------- prep 2: codebook MFMA A-fragments (hi/lo bf16) ----------------
// frag index ((t*2+c)*64 + lane): 8 bf16 = A[m = t*16+(lane&15)][k = c*32+quad*8+j]
__global__ __launch_bounds__(512) void vq_prep2(const float* __restrict__ emb,
                                                float* __restrict__ wsf) {
    int tid = blockIdx.x * 512 + threadIdx.x;   // 0..4095
    if (tid >= 32 * 2 * 64) return;
    int l = tid & 63;
    int c = (tid >> 6) & 1;
    int t = tid >> 7;
    int m = t * 16 + (l & 15);
    int dbase = c * 32 + ((l >> 4) & 3) * 8;
    unsigned hh[4], ll[4];
    #pragma unroll
    for (int j2 = 0; j2 < 4; ++j2) {
        float f0 = emb[(dbase + 2 * j2 + 0) * KCB + m];
        float f1 = emb[(dbase + 2 * j2 + 1) * KCB + m];
        unsigned short h0 = f2bf_rne(f0), h1 = f2bf_rne(f1);
        unsigned short l0 = f2bf_rne(f0 - bf2f(h0)), l1 = f2bf_rne(f1 - bf2f(h1));
        hh[j2] = (unsigned)h0 | ((unsigned)h1 << 16);
        ll[j2] = (unsigned)l0 | ((unsigned)l1 << 16);
    }
    uint4* ehp = (uint4*)(wsf + WS_EH);
    uint4* elp = (uint4*)(wsf + WS_EL);
    ehp[tid] = make_uint4(hh[0], hh[1], hh[2], hh[3]);
    elp[tid] = make_uint4(ll[0], ll[1], ll[2], ll[3]);
}

// ---------------- main: 512-thread block = 8 waves, eh in LDS, el global ----------------
// Each wave handles 32 rows vs all 512 codes. LDS: eh 64KB + cn 2KB = 66KB
// -> 2 blocks/CU co-resident: one block's t-loop overlaps the other's
// x-load/write phases. 1024 blocks for balance.
__global__ __launch_bounds__(512) void vq_main_mfma(const float* __restrict__ x,
                                                    const float* __restrict__ wsf,
                                                    float* __restrict__ out,
                                                    float* __restrict__ loss_accum) {
    const int lane = threadIdx.x & 63;
    const int quad = lane >> 4;
    const int wid  = threadIdx.x >> 6;
    const int nbase = blockIdx.x * 256 + wid * 32;

    __shared__ uint4  sh_eh[32 * 2 * 64];   // 64 KB
    __shared__ float4 sh_cn[128];           // 2 KB: -0.5 * ||e||^2

    // ---- stage eh fragments + scaled norms into LDS (once per block) ----
    {
        const uint4* geh = (const uint4*)(wsf + WS_EH);
        const int tid = threadIdx.x;
        #pragma unroll
        for (int i = 0; i < 8; ++i)
            sh_eh[tid + i * 512] = geh[tid + i * 512];
        if (tid < 128) {
            float4 c = ((const float4*)(wsf + WS_CNORM))[tid];
            sh_cn[tid] = make_float4(-0.5f * c.x, -0.5f * c.y,
                                     -0.5f * c.z, -0.5f * c.w);
        }
    }

    const float* __restrict__ et = wsf + WS_ET;
    const bf16x8* __restrict__ gel = (const bf16x8*)(wsf + WS_EL);

    // ---- load 32 x rows, build B-fragments (hi/lo), accumulate ||x||^2 ----
    // (overlaps the LDS staging; barrier after)
    bf16x8 xh[2][2], xl[2][2];
    float xnorm[2];
    #pragma unroll
    for (int j = 0; j < 2; ++j) {
        float s = 0.f;
        #pragma unroll
        for (int c = 0; c < 2; ++c) {
            const float* xrow = x + (size_t)(nbase + j * 16 + (lane & 15)) * DDIM
                                  + c * 32 + quad * 8;
            float4 xa = *(const float4*)xrow;
            float4 xb = *(const float4*)(xrow + 4);
            s += xa.x * xa.x + xa.y * xa.y + xa.z * xa.z + xa.w * xa.w;
            s += xb.x * xb.x + xb.y * xb.y + xb.z * xb.z + xb.w * xb.w;
            float f[8] = {xa.x, xa.y, xa.z, xa.w, xb.x, xb.y, xb.z, xb.w};
            union { bf16x8 v; unsigned short u[8]; } H, L;
            #pragma unroll
            for (int e = 0; e < 8; ++e) {
                unsigned short h = f2bf_rne(f[e]);
                H.u[e] = h;
                L.u[e] = f2bf_rne(f[e] - bf2f(h));
            }
            xh[j][c] = H.v;
            xl[j][c] = L.v;
        }
        // sum partial ||x||^2 across the 4 quads (bits 4,5 of lane)
        s += __shfl_xor(s, 16);
        s += __shfl_xor(s, 32);
        xnorm[j] = s;
    }

    __syncthreads();

    const bf16x8* __restrict__ ehv = (const bf16x8*)sh_eh;

    // ---- argmax of score = sim - 0.5*||e||^2 over 32 code-tiles ----
    float best[2], second[2];
    int bestv[2];  // t*16 + reg  (full code = bestv + quad*4)
    #pragma unroll
    for (int j = 0; j < 2; ++j) { best[j] = -3.4e38f; second[j] = -3.4e38f; bestv[j] = 0; }

    // prefetched el fragments for tile t (global, L2-hot)
    bf16x8 el0 = gel[lane], el1 = gel[64 + lane];

    #pragma unroll 1
    for (int t = 0; t < 32; ++t) {
        // prefetch el for t+1 (wraps on last iter; harmless, unused)
        const int tn = (t + 1) & 31;
        bf16x8 nel0 = gel[(tn * 2 + 0) * 64 + lane];
        bf16x8 nel1 = gel[(tn * 2 + 1) * 64 + lane];
        // eh for this tile from LDS (issued at iter top; ~120cy covered by TLP)
        bf16x8 eh0 = ehv[(t * 2 + 0) * 64 + lane];
        bf16x8 eh1 = ehv[(t * 2 + 1) * 64 + lane];
        float4 cn = sh_cn[t * 4 + quad];
        const int kb = t * 16;
        #pragma unroll
        for (int j = 0; j < 2; ++j) {
            // 3 independent 2-deep MFMA chains (was one 6-deep chain)
            f32x4 accA = {cn.x, cn.y, cn.z, cn.w};   // carries -0.5*||e||^2
            f32x4 accB = {0.f, 0.f, 0.f, 0.f};
            f32x4 accC = {0.f, 0.f, 0.f, 0.f};
            accA = __builtin_amdgcn_mfma_f32_16x16x32_bf16(eh0, xh[j][0], accA, 0, 0, 0);
            accB = __builtin_amdgcn_mfma_f32_16x16x32_bf16(el0, xh[j][0], accB, 0, 0, 0);
            accC = __builtin_amdgcn_mfma_f32_16x16x32_bf16(eh0, xl[j][0], accC, 0, 0, 0);
            accA = __builtin_amdgcn_mfma_f32_16x16x32_bf16(eh1, xh[j][1], accA, 0, 0, 0);
            accB = __builtin_amdgcn_mfma_f32_16x16x32_bf16(el1, xh[j][1], accB, 0, 0, 0);
            accC = __builtin_amdgcn_mfma_f32_16x16x32_bf16(eh1, xl[j][1], accC, 0, 0, 0);
            #pragma unroll
            for (int r = 0; r < 4; ++r) {
                float s = (accA[r] + accB[r]) + accC[r];
                // new second = median(s, best, second) given best >= second
                second[j] = __builtin_amdgcn_fmed3f(s, best[j], second[j]);
                bool gt = s > best[j];
                bestv[j] = gt ? (kb + r) : bestv[j];
                best[j] = fmaxf(best[j], s);
            }
        }
        el0 = nel0; el1 = nel1;
    }

    // ---- reduce across the 4 quads (lanes n, n+16, n+32, n+48) ----
    int bk[2];
    #pragma unroll
    for (int j = 0; j < 2; ++j) bk[j] = bestv[j] + quad * 4;
    #pragma unroll
    for (int j = 0; j < 2; ++j) {
        #pragma unroll
        for (int m = 16; m <= 32; m <<= 1) {
            float ob = __shfl_xor(best[j], m);
            float os = __shfl_xor(second[j], m);
            int   ok = __shfl_xor(bk[j], m);
            float nb = fmaxf(best[j], ob);
            float ns = fmaxf(fmaxf(second[j], os), fminf(best[j], ob));
            bool take = (ob > best[j]) || (ob == best[j] && ok < bk[j]);
            bk[j] = take ? ok : bk[j];
            best[j] = nb;
            second[j] = ns;
        }
    }

    // ---- back to distance domain: dist = -2*score  (||x||^2 dropped) ----
    float bd[2], sd[2];
    #pragma unroll
    for (int j = 0; j < 2; ++j) { bd[j] = -2.f * best[j]; sd[j] = -2.f * second[j]; }

    // ---- near-tie: whole-wave cooperative exact fp64 rescan (rare) ----
    #pragma unroll
    for (int j = 0; j < 2; ++j) {
        unsigned long long need = __ballot(sd[j] - bd[j] < TIE_TH) & 0xFFFFULL;
        while (need) {
            int nl = __ffsll(need) - 1;
            need &= need - 1;
            const float* xr = x + (size_t)(nbase + j * 16 + nl) * DDIM;
            double dmin = 1e300;
            int kmin = 0;
            #pragma unroll
            for (int i = 0; i < 8; ++i) {
                int k = lane * 8 + i;
                const float* er = et + k * DDIM;
                double s = 0.0;
                for (int d4 = 0; d4 < 16; ++d4) {
                    float4 xv = *(const float4*)(xr + d4 * 4);
                    float4 ev = *(const float4*)(er + d4 * 4);
                    double a = (double)xv.x - (double)ev.x; s += a * a;
                    double b = (double)xv.y - (double)ev.y; s += b * b;
                    double c = (double)xv.z - (double)ev.z; s += c * c;
                    double e = (double)xv.w - (double)ev.w; s += e * e;
                }
                if (s < dmin) { dmin = s; kmin = k; }
            }
            #pragma unroll
            for (int m = 1; m < 64; m <<= 1) {
                double od = __shfl_xor(dmin, m);
                int   ok = __shfl_xor(kmin, m);
                if (od < dmin || (od == dmin && ok < kmin)) { dmin = od; kmin = ok; }
            }
            if ((lane & 15) == nl) {
                bk[j] = kmin;
                bd[j] = (float)dmin - xnorm[j];  // keep loss exact
            }
        }
    }

    // ---- loss partial: sum (q-x)^2 = xnorm + bd over this wave's 32 n ----
    float ls = 0.f;
    if (lane < 16) {
        #pragma unroll
        for (int j = 0; j < 2; ++j) ls += fmaxf(xnorm[j] + bd[j], 0.f);
    }
    #pragma unroll
    for (int m = 1; m < 64; m <<= 1) ls += __shfl_xor(ls, m);
    if (lane == 0) atomicAdd(loss_accum, ls);

    // ---- write quantized rows: lane -> (n = lane>>2, 64B slice = lane&3) ----
    #pragma unroll
    for (int j = 0; j < 2; ++j) {
        int bkn = __shfl(bk[j], lane >> 2);
        const float4* er = (const float4*)(et + (size_t)bkn * DDIM + (lane & 3) * 16);
        float4* op = (float4*)(out + (size_t)(nbase + j * 16 + (lane >> 2)) * DDIM
                                   + (lane & 3) * 16);
        op[0] = er[0]; op[1] = er[1]; op[2] = er[2]; op[3] = er[3];
    }
}

// ---------------- legacy fallback (round-1 kernel) if ws is too small ----------------
__global__ __launch_bounds__(256) void vq_main_legacy(const float* __restrict__ x,
                                                      const float* __restrict__ emb,
                                                      const float* __restrict__ wsf,
                                                      float* __restrict__ out,
                                                      float* __restrict__ loss_accum) {
    const int n = blockIdx.x * 256 + threadIdx.x;
    const float* __restrict__ cnorm = wsf + WS_CNORM;
    const float* __restrict__ et    = wsf + WS_ET;
    float xr[DDIM];
    {
        const float4* xp = (const float4*)(x + (size_t)n * DDIM);
        #pragma unroll
        for (int d4 = 0; d4 < DDIM / 4; ++d4) {
            float4 v = xp[d4];
            xr[4 * d4 + 0] = v.x; xr[4 * d4 + 1] = v.y;
            xr[4 * d4 + 2] = v.z; xr[4 * d4 + 3] = v.w;
        }
    }
    float best = 3.4e38f, second = 3.4e38f;
    int bestk = 0;
    for (int k0 = 0; k0 < KCB; k0 += 8) {
        float acc[8];
        #pragma unroll
        for (int j = 0; j < 8; ++j) acc[j] = 0.f;
        #pragma unroll
        for (int j = 0; j < 8; ++j) {
            const float* ek = et + (k0 + j) * DDIM;
            float s = 0.f;
            #pragma unroll
            for (int d = 0; d < DDIM; ++d) s += xr[d] * ek[d];
            acc[j] = s;
        }
        #pragma unroll
        for (int j = 0; j < 8; ++j) {
            float dist = cnorm[k0 + j] - 2.f * acc[j];
            if (dist < best) { second = best; best = dist; bestk = k0 + j; }
            else if (dist < second) { second = dist; }
        }
    }
    if (second - best < TIE_TH) {
        double bestd = 1e300;
        int bkk = 0;
        for (int k = 0; k < KCB; ++k) {
            const float* ek = et + k * DDIM;
            double s = 0.0;
            #pragma unroll
            for (int d = 0; d < DDIM; ++d) {
                double diff = (double)xr[d] - (double)ek[d];
                s += diff * diff;
            }
            if (s < bestd) { bestd = s; bkk = k; }
        }
        bestk = bkk;
    }
    float sq = 0.f;
    {
        const float4* qp = (const float4*)(et + bestk * DDIM);
        float4* op = (float4*)(out + (size_t)n * DDIM);
        #pragma unroll
        for (int d4 = 0; d4 < DDIM / 4; ++d4) {
            float4 q = qp[d4];
            op[d4] = q;
            float a = q.x - xr[4 * d4 + 0];
            float b = q.y - xr[4 * d4 + 1];
            float c = q.z - xr[4 * d4 + 2];
            float e = q.w - xr[4 * d4 + 3];
            sq += a * a + b * b + c * c + e * e;
        }
    }
    #pragma unroll
    for (int off = 32; off > 0; off >>= 1) sq += __shfl_down(sq, off);
    __shared__ float red[4];
    const int lane = threadIdx.x & 63;
    const int wid  = threadIdx.x >> 6;
    if (lane == 0) red[wid] = sq;
    __syncthreads();
    if (threadIdx.x == 0) atomicAdd(loss_accum, red[0] + red[1] + red[2] + red[3]);
}

__global__ void vq_final(const float* __restrict__ loss_accum,
                         float* __restrict__ out) {
    out[(size_t)NVEC * DDIM] = 1.25f * loss_accum[0] / 16777216.f;
}

extern "C" void kernel_launch(void* const* d_in, const int* in_sizes, int n_in,
                              void* d_out, int out_size, void* d_ws, size_t ws_size,
                              hipStream_t stream) {
    const float* x   = (const float*)d_in[0];
    const float* emb = (const float*)d_in[1];
    float* out = (float*)d_out;
    float* wsf = (float*)d_ws;

    vq_prep1<<<1, 512, 0, stream>>>(emb, wsf);
    if (ws_size >= (size_t)WS_END * 4) {
        vq_prep2<<<8, 512, 0, stream>>>(emb, wsf);
        vq_main_mfma<<<NVEC / 256, 512, 0, stream>>>(x, wsf, out, wsf + WS_LOSS);
    } else {
        vq_main_legacy<<<NVEC / 256, 256, 0, stream>>>(x, emb, wsf, out, wsf + WS_LOSS);
    }
    vq_final<<<1, 1, 0, stream>>>(wsf + WS_LOSS, out);
}

// Round 5
// 233.093 us; speedup vs baseline: 1.0413x; 1.0413x over previous
//
#include <hip/hip_runtime.h>

// VectorQuantizer on MI355X (gfx950) — round 7: j=4 fat-register waves + launch-overhead trim
// x: [262144, 64] fp32; embeddings: [64, 512] fp32 (codes are COLUMNS)
// out: quantized [N*64] fp32 ++ loss scalar
//
// sim = x.e computed as xh.eh + xl.eh + xh.el (bf16 split, abs err ~3e-5)
// score = sim - 0.5*||e||^2  (accumulator-initialized; argmax == argmin dist)
//
// Round-7 vs round-6 (main 154us / bench 242us) and round-4 (main 115 / bench 210):
//   Re-derived floors: MFMA-pipe floor = 24.8us (3.15M mfma x 4.85cyc/CU);
//   ~90us of every bench is prep/final/launch overhead, not the main kernel.
//   1. MAIN: 256-thread blocks (4 waves, j=4 -> 64 rows/wave). LDS = eh(64KB)+cn
//      -> 2 blocks/CU = 8 waves/CU. j=4 halves LDS-read demand per MFMA
//      (r4's j=2/16-wave shape was LDS-pipe co-critical: 768 vs 931 cyc/window).
//      el fragments from global (64KB, L2-resident) with 2-DEEP register
//      prefetch (covers ~200cy L2 latency; r6's 1-deep got sunk by the
//      60-reg allocator). __launch_bounds__(256,2) -> VGPR cap 256, live set
//      ~170 fits (256-thr blocks escape the 64-reg jail: r2 got 96+).
//   2. OVERHEAD: prep1+prep2 merged into ONE 8-block kernel (et/cnorm
//      parallelized 8x512 instead of 1x512); vq_final folded into main via
//      threadfence + done-counter (last block writes the loss) -> two fewer
//      launch drains.
// near-tie (gap < 1e-3): whole-wave cooperative exact fp64 rescan (rare)

#define NVEC 262144
#define DDIM 64
#define KCB  512
#define TIE_TH 1e-3f

// ws layout (4-byte units)
#define WS_LOSS  0
#define WS_DONE  1                       // done-block counter (uint)
#define WS_CNORM 64                      // 512 floats
#define WS_ET    1024                    // 512*64 floats (code-major codebook)
#define WS_EH    (WS_ET + KCB * DDIM)    // 32 tiles * 2 chunks * 64 lanes * 16B
#define WS_EL    (WS_EH + 32 * 2 * 64 * 4)
#define WS_END   (WS_EL + 32 * 2 * 64 * 4)

typedef __attribute__((ext_vector_type(8))) short bf16x8;
typedef __attribute__((ext_vector_type(4))) float f32x4;

static __device__ __forceinline__ unsigned short f2bf_rne(float f) {
    unsigned u = __float_as_uint(f);
    unsigned r = (u + 0x7FFFu + ((u >> 16) & 1u)) >> 16;
    return (unsigned short)r;
}
static __device__ __forceinline__ float bf2f(unsigned short h) {
    return __uint_as_float(((unsigned)h) << 16);
}

// ---------------- merged prep: et, cnorm, fragments, zero loss+counter ----------------
// grid 8 x 512. tid 0..4095.
__global__ __launch_bounds__(512) void vq_prep(const float* __restrict__ emb,
                                               float* __restrict__ wsf) {
    const int tid = blockIdx.x * 512 + threadIdx.x;   // 0..4095

    // ---- part B: et (code-major) + cnorm, 8 threads per code ----
    {
        int k  = tid >> 3;            // 0..511
        int d0 = (tid & 7) * 8;
        float s = 0.f;
        float* et = wsf + WS_ET;
        #pragma unroll
        for (int i = 0; i < 8; ++i) {
            float e = emb[(d0 + i) * KCB + k];
            s += e * e;
            et[k * DDIM + d0 + i] = e;
        }
        s += __shfl_xor(s, 1);
        s += __shfl_xor(s, 2);
        s += __shfl_xor(s, 4);
        if ((tid & 7) == 0) wsf[WS_CNORM + k] = s;
        if (tid == 0) {
            wsf[WS_LOSS] = 0.f;
            ((unsigned*)wsf)[WS_DONE] = 0u;
        }
    }

    // ---- part A: codebook MFMA A-fragments (hi/lo bf16) ----
    // frag index ((t*2+c)*64 + lane): 8 bf16 = A[m=t*16+(lane&15)][k=c*32+quad*8+j]
    {
        int l = tid & 63;
        int c = (tid >> 6) & 1;
        int t = tid >> 7;
        int m = t * 16 + (l & 15);
        int dbase = c * 32 + ((l >> 4) & 3) * 8;
        unsigned hh[4], ll[4];
        #pragma unroll
        for (int j2 = 0; j2 < 4; ++j2) {
            float f0 = emb[(dbase + 2 * j2 + 0) * KCB + m];
            float f1 = emb[(dbase + 2 * j2 + 1) * KCB + m];
            unsigned short h0 = f2bf_rne(f0), h1 = f2bf_rne(f1);
            unsigned short l0 = f2bf_rne(f0 - bf2f(h0)), l1 = f2bf_rne(f1 - bf2f(h1));
            hh[j2] = (unsigned)h0 | ((unsigned)h1 << 16);
            ll[j2] = (unsigned)l0 | ((unsigned)l1 << 16);
        }
        uint4* ehp = (uint4*)(wsf + WS_EH);
        uint4* elp = (uint4*)(wsf + WS_EL);
        ehp[tid] = make_uint4(hh[0], hh[1], hh[2], hh[3]);
        elp[tid] = make_uint4(ll[0], ll[1], ll[2], ll[3]);
    }
}

// ---------------- main: 256-thr block = 4 waves, j=4 (64 rows/wave) ----------------
// LDS: eh 64KB + cn 2KB (+16B) -> 2 blocks/CU = 8 waves/CU.
// el fragments from global (L2-resident 64KB) with 2-deep register prefetch.
// Last block to finish writes the loss scalar (vq_final folded in).
__global__ __launch_bounds__(256, 2) void vq_main_mfma(const float* __restrict__ x,
                                                       float* __restrict__ wsf,
                                                       float* __restrict__ out) {
    const int lane = threadIdx.x & 63;
    const int quad = lane >> 4;
    const int wid  = threadIdx.x >> 6;          // 0..3
    const int nbase = blockIdx.x * 256 + wid * 64;

    __shared__ uint4  sh_eh[32 * 2 * 64];   // 64 KB
    __shared__ float4 sh_cn[128];           // 2 KB: -0.5 * ||e||^2
    __shared__ float  redls[4];

    // ---- stage eh fragments + scaled norms into LDS (once per block) ----
    {
        const uint4* geh = (const uint4*)(wsf + WS_EH);
        const int tid = threadIdx.x;
        #pragma unroll
        for (int i = 0; i < 16; ++i)
            sh_eh[tid + i * 256] = geh[tid + i * 256];
        if (tid < 128) {
            float4 c = ((const float4*)(wsf + WS_CNORM))[tid];
            sh_cn[tid] = make_float4(-0.5f * c.x, -0.5f * c.y,
                                     -0.5f * c.z, -0.5f * c.w);
        }
    }

    const float* __restrict__ et = wsf + WS_ET;
    const bf16x8* __restrict__ gel = (const bf16x8*)(wsf + WS_EL);
    float* __restrict__ loss_accum = wsf + WS_LOSS;

    // ---- load 64 x rows, build B-fragments (hi/lo), accumulate ||x||^2 ----
    // (overlaps the LDS staging; barrier after)
    bf16x8 xh[4][2], xl[4][2];
    float xnorm[4];
    #pragma unroll
    for (int j = 0; j < 4; ++j) {
        float s = 0.f;
        #pragma unroll
        for (int c = 0; c < 2; ++c) {
            const float* xrow = x + (size_t)(nbase + j * 16 + (lane & 15)) * DDIM
                                  + c * 32 + quad * 8;
            float4 xa = *(const float4*)xrow;
            float4 xb = *(const float4*)(xrow + 4);
            s += xa.x * xa.x + xa.y * xa.y + xa.z * xa.z + xa.w * xa.w;
            s += xb.x * xb.x + xb.y * xb.y + xb.z * xb.z + xb.w * xb.w;
            float f[8] = {xa.x, xa.y, xa.z, xa.w, xb.x, xb.y, xb.z, xb.w};
            union { bf16x8 v; unsigned short u[8]; } H, L;
            #pragma unroll
            for (int e = 0; e < 8; ++e) {
                unsigned short h = f2bf_rne(f[e]);
                H.u[e] = h;
                L.u[e] = f2bf_rne(f[e] - bf2f(h));
            }
            xh[j][c] = H.v;
            xl[j][c] = L.v;
        }
        s += __shfl_xor(s, 16);
        s += __shfl_xor(s, 32);
        xnorm[j] = s;
    }

    __syncthreads();

    const bf16x8* __restrict__ ehv = (const bf16x8*)sh_eh;

    // ---- argmax of score = sim - 0.5*||e||^2 over 32 code-tiles ----
    float best[4], second[4];
    int bestv[4];  // t*16 + reg  (full code = bestv + quad*4)
    #pragma unroll
    for (int j = 0; j < 4; ++j) { best[j] = -3.4e38f; second[j] = -3.4e38f; bestv[j] = 0; }

    // prefetch: el 2-deep (global, ~200cy), eh 1-deep (LDS, ~120cy)
    bf16x8 elc0 = gel[0 * 64 + lane], elc1 = gel[1 * 64 + lane];   // t
    bf16x8 eln0 = gel[2 * 64 + lane], eln1 = gel[3 * 64 + lane];   // t+1
    bf16x8 ehc0 = ehv[0 * 64 + lane], ehc1 = ehv[1 * 64 + lane];   // t

    #pragma unroll 1
    for (int t = 0; t < 32; ++t) {
        const int t2 = (t + 2) & 31;
        const int t1 = (t + 1) & 31;
        bf16x8 elq0 = gel[(t2 * 2 + 0) * 64 + lane];   // t+2 (wraps, unused tail ok)
        bf16x8 elq1 = gel[(t2 * 2 + 1) * 64 + lane];
        bf16x8 ehn0 = ehv[(t1 * 2 + 0) * 64 + lane];
        bf16x8 ehn1 = ehv[(t1 * 2 + 1) * 64 + lane];
        float4 cn = sh_cn[t * 4 + quad];
        const int kb = t * 16;
        #pragma unroll
        for (int j = 0; j < 4; ++j) {
            // 3 independent 2-deep MFMA chains per j
            f32x4 accA = {cn.x, cn.y, cn.z, cn.w};   // carries -0.5*||e||^2
            f32x4 accB = {0.f, 0.f, 0.f, 0.f};
            f32x4 accC = {0.f, 0.f, 0.f, 0.f};
            accA = __builtin_amdgcn_mfma_f32_16x16x32_bf16(ehc0, xh[j][0], accA, 0, 0, 0);
            accB = __builtin_amdgcn_mfma_f32_16x16x32_bf16(elc0, xh[j][0], accB, 0, 0, 0);
            accC = __builtin_amdgcn_mfma_f32_16x16x32_bf16(ehc0, xl[j][0], accC, 0, 0, 0);
            accA = __builtin_amdgcn_mfma_f32_16x16x32_bf16(ehc1, xh[j][1], accA, 0, 0, 0);
            accB = __builtin_amdgcn_mfma_f32_16x16x32_bf16(elc1, xh[j][1], accB, 0, 0, 0);
            accC = __builtin_amdgcn_mfma_f32_16x16x32_bf16(ehc1, xl[j][1], accC, 0, 0, 0);
            #pragma unroll
            for (int r = 0; r < 4; ++r) {
                float s = (accA[r] + accB[r]) + accC[r];
                // new second = median(s, best, second) given best >= second
                second[j] = __builtin_amdgcn_fmed3f(s, best[j], second[j]);
                bool gt = s > best[j];
                bestv[j] = gt ? (kb + r) : bestv[j];
                best[j] = fmaxf(best[j], s);
            }
        }
        ehc0 = ehn0; ehc1 = ehn1;
        elc0 = eln0; elc1 = eln1;
        eln0 = elq0; eln1 = elq1;
    }

    // ---- reduce across the 4 quads (lanes n, n+16, n+32, n+48) ----
    int bk[4];
    #pragma unroll
    for (int j = 0; j < 4; ++j) bk[j] = bestv[j] + quad * 4;
    #pragma unroll
    for (int j = 0; j < 4; ++j) {
        #pragma unroll
        for (int m = 16; m <= 32; m <<= 1) {
            float ob = __shfl_xor(best[j], m);
            float os = __shfl_xor(second[j], m);
            int   ok = __shfl_xor(bk[j], m);
            float nb = fmaxf(best[j], ob);
            float ns = fmaxf(fmaxf(second[j], os), fminf(best[j], ob));
            bool take = (ob > best[j]) || (ob == best[j] && ok < bk[j]);
            bk[j] = take ? ok : bk[j];
            best[j] = nb;
            second[j] = ns;
        }
    }

    // ---- back to distance domain: dist = -2*score  (||x||^2 dropped) ----
    float bd[4], sd[4];
    #pragma unroll
    for (int j = 0; j < 4; ++j) { bd[j] = -2.f * best[j]; sd[j] = -2.f * second[j]; }

    // ---- near-tie: whole-wave cooperative exact fp64 rescan (rare) ----
    #pragma unroll
    for (int j = 0; j < 4; ++j) {
        unsigned long long need = __ballot(sd[j] - bd[j] < TIE_TH) & 0xFFFFULL;
        while (need) {
            int nl = __ffsll(need) - 1;
            need &= need - 1;
            const float* xr = x + (size_t)(nbase + j * 16 + nl) * DDIM;
            double dmin = 1e300;
            int kmin = 0;
            #pragma unroll
            for (int i = 0; i < 8; ++i) {
                int k = lane * 8 + i;
                const float* er = et + k * DDIM;
                double s = 0.0;
                for (int d4 = 0; d4 < 16; ++d4) {
                    float4 xv = *(const float4*)(xr + d4 * 4);
                    float4 ev = *(const float4*)(er + d4 * 4);
                    double a = (double)xv.x - (double)ev.x; s += a * a;
                    double b = (double)xv.y - (double)ev.y; s += b * b;
                    double c = (double)xv.z - (double)ev.z; s += c * c;
                    double e = (double)xv.w - (double)ev.w; s += e * e;
                }
                if (s < dmin) { dmin = s; kmin = k; }
            }
            #pragma unroll
            for (int m = 1; m < 64; m <<= 1) {
                double od = __shfl_xor(dmin, m);
                int   ok = __shfl_xor(kmin, m);
                if (od < dmin || (od == dmin && ok < kmin)) { dmin = od; kmin = ok; }
            }
            if ((lane & 15) == nl) {
                bk[j] = kmin;
                bd[j] = (float)dmin - xnorm[j];  // keep loss exact
            }
        }
    }

    // ---- loss partial: sum (q-x)^2 = xnorm + bd over this wave's 64 n ----
    float ls = 0.f;
    if (lane < 16) {
        #pragma unroll
        for (int j = 0; j < 4; ++j) ls += fmaxf(xnorm[j] + bd[j], 0.f);
    }
    #pragma unroll
    for (int m = 1; m < 64; m <<= 1) ls += __shfl_xor(ls, m);
    if (lane == 0) redls[wid] = ls;
    __syncthreads();
    if (threadIdx.x == 0) {
        float Lb = (redls[0] + redls[1]) + (redls[2] + redls[3]);
        atomicAdd(loss_accum, Lb);
        __threadfence();
        unsigned d = atomicAdd((unsigned*)wsf + WS_DONE, 1u);
        if (d == gridDim.x - 1) {
            // all blocks' loss atomics are fenced-before their counter adds
            float L = atomicAdd(loss_accum, 0.f);   // coherent read-back
            out[(size_t)NVEC * DDIM] = 1.25f * L / 16777216.f;
        }
    }

    // ---- write quantized rows: lane -> (n = lane>>2, 64B slice = lane&3) ----
    #pragma unroll
    for (int j = 0; j < 4; ++j) {
        int bkn = __shfl(bk[j], lane >> 2);
        const float4* er = (const float4*)(et + (size_t)bkn * DDIM + (lane & 3) * 16);
        float4* op = (float4*)(out + (size_t)(nbase + j * 16 + (lane >> 2)) * DDIM
                                   + (lane & 3) * 16);
        op[0] = er[0]; op[1] = er[1]; op[2] = er[2]; op[3] = er[3];
    }
}

// ---------------- legacy fallback path (ws too small for fragment tables) ----------------
__global__ __launch_bounds__(512) void vq_prep1(const float* __restrict__ emb,
                                                float* __restrict__ wsf) {
    int k = threadIdx.x;
    float s = 0.f;
    float* et = wsf + WS_ET;
    #pragma unroll
    for (int d = 0; d < DDIM; ++d) {
        float e = emb[d * KCB + k];
        s += e * e;
        et[k * DDIM + d] = e;
    }
    wsf[WS_CNORM + k] = s;
    if (k == 0) wsf[WS_LOSS] = 0.f;
}

__global__ __launch_bounds__(256) void vq_main_legacy(const float* __restrict__ x,
                                                      const float* __restrict__ emb,
                                                      const float* __restrict__ wsf,
                                                      float* __restrict__ out,
                                                      float* __restrict__ loss_accum) {
    const int n = blockIdx.x * 256 + threadIdx.x;
    const float* __restrict__ cnorm = wsf + WS_CNORM;
    const float* __restrict__ et    = wsf + WS_ET;
    float xr[DDIM];
    {
        const float4* xp = (const float4*)(x + (size_t)n * DDIM);
        #pragma unroll
        for (int d4 = 0; d4 < DDIM / 4; ++d4) {
            float4 v = xp[d4];
            xr[4 * d4 + 0] = v.x; xr[4 * d4 + 1] = v.y;
            xr[4 * d4 + 2] = v.z; xr[4 * d4 + 3] = v.w;
        }
    }
    float best = 3.4e38f, second = 3.4e38f;
    int bestk = 0;
    for (int k0 = 0; k0 < KCB; k0 += 8) {
        float acc[8];
        #pragma unroll
        for (int j = 0; j < 8; ++j) {
            const float* ek = et + (k0 + j) * DDIM;
            float s = 0.f;
            #pragma unroll
            for (int d = 0; d < DDIM; ++d) s += xr[d] * ek[d];
            acc[j] = s;
        }
        #pragma unroll
        for (int j = 0; j < 8; ++j) {
            float dist = cnorm[k0 + j] - 2.f * acc[j];
            if (dist < best) { second = best; best = dist; bestk = k0 + j; }
            else if (dist < second) { second = dist; }
        }
    }
    if (second - best < TIE_TH) {
        double bestd = 1e300;
        int bkk = 0;
        for (int k = 0; k < KCB; ++k) {
            const float* ek = et + k * DDIM;
            double s = 0.0;
            #pragma unroll
            for (int d = 0; d < DDIM; ++d) {
                double diff = (double)xr[d] - (double)ek[d];
                s += diff * diff;
            }
            if (s < bestd) { bestd = s; bkk = k; }
        }
        bestk = bkk;
    }
    float sq = 0.f;
    {
        const float4* qp = (const float4*)(et + bestk * DDIM);
        float4* op = (float4*)(out + (size_t)n * DDIM);
        #pragma unroll
        for (int d4 = 0; d4 < DDIM / 4; ++d4) {
            float4 q = qp[d4];
            op[d4] = q;
            float a = q.x - xr[4 * d4 + 0];
            float b = q.y - xr[4 * d4 + 1];
            float c = q.z - xr[4 * d4 + 2];
            float e = q.w - xr[4 * d4 + 3];
            sq += a * a + b * b + c * c + e * e;
        }
    }
    #pragma unroll
    for (int off = 32; off > 0; off >>= 1) sq += __shfl_down(sq, off);
    __shared__ float red[4];
    const int lane = threadIdx.x & 63;
    const int wid  = threadIdx.x >> 6;
    if (lane == 0) red[wid] = sq;
    __syncthreads();
    if (threadIdx.x == 0) atomicAdd(loss_accum, red[0] + red[1] + red[2] + red[3]);
}

__global__ void vq_final(const float* __restrict__ loss_accum,
                         float* __restrict__ out) {
    out[(size_t)NVEC * DDIM] = 1.25f * loss_accum[0] / 16777216.f;
}

extern "C" void kernel_launch(void* const* d_in, const int* in_sizes, int n_in,
                              void* d_out, int out_size, void* d_ws, size_t ws_size,
                              hipStream_t stream) {
    const float* x   = (const float*)d_in[0];
    const float* emb = (const float*)d_in[1];
    float* out = (float*)d_out;
    float* wsf = (float*)d_ws;

    if (ws_size >= (size_t)WS_END * 4) {
        vq_prep<<<8, 512, 0, stream>>>(emb, wsf);
        vq_main_mfma<<<NVEC / 256, 256, 0, stream>>>(x, wsf, out);
        // loss written by last finishing block of vq_main_mfma
    } else {
        vq_prep1<<<1, 512, 0, stream>>>(emb, wsf);
        vq_main_legacy<<<NVEC / 256, 256, 0, stream>>>(x, emb, wsf, out, wsf + WS_LOSS);
        vq_final<<<1, 1, 0, stream>>>(wsf + WS_LOSS, out);
    }
}

// Round 6
// 188.950 us; speedup vs baseline: 1.2846x; 1.2336x over previous
//
#include <hip/hip_runtime.h>

// VectorQuantizer on MI355X (gfx950) — round 8: r4 structure + real 128-reg cap
// x: [262144, 64] fp32; embeddings: [64, 512] fp32 (codes are COLUMNS)
// out: quantized [N*64] fp32 ++ loss scalar
//
// sim = x.e computed as xh.eh + xl.eh + xh.el (bf16 split, abs err ~3e-5)
// score = sim - 0.5*||e||^2  (accumulator-initialized; argmax == argmin dist)
//
// Round-8: revert to the measured-best main structure (r4, 115us: 1024-thr,
// j=2, BOTH fragment tables in LDS, 2 passes) and fix its one known defect:
// plain __launch_bounds__(1024) let the allocator pick 64 VGPRs (heuristic
// targets 8 waves/EU it can never have; 130KB LDS pins 1 block/CU = 4/EU),
// spilling ~12 regs (WRITE 79MB vs 66 real). __launch_bounds__(1024, 4)
// declares min-waves/EU = 4 -> reg cap 512/4 = 128 >= the ~105-reg j=2 live
// set -> no spill, and the 1-deep LDS prefetch survives scheduling.
// (r3 tried (1024,4) with j=4's ~160-reg live set -> forced spill; r6/r7's
// el-from-global both regressed -> both tables stay in LDS.)
// Keeps r7's proven overhead trims: merged 8-block prep, vq_final folded into
// main via done-counter (bench-gap 93 -> 81us).
// near-tie (gap < 1e-3): whole-wave cooperative exact fp64 rescan (rare)

#define NVEC 262144
#define DDIM 64
#define KCB  512
#define TIE_TH 1e-3f

// ws layout (4-byte units)
#define WS_LOSS  0
#define WS_DONE  1                       // done-block counter (uint)
#define WS_CNORM 64                      // 512 floats
#define WS_ET    1024                    // 512*64 floats (code-major codebook)
#define WS_EH    (WS_ET + KCB * DDIM)    // 32 tiles * 2 chunks * 64 lanes * 16B
#define WS_EL    (WS_EH + 32 * 2 * 64 * 4)
#define WS_END   (WS_EL + 32 * 2 * 64 * 4)

typedef __attribute__((ext_vector_type(8))) short bf16x8;
typedef __attribute__((ext_vector_type(4))) float f32x4;

static __device__ __forceinline__ unsigned short f2bf_rne(float f) {
    unsigned u = __float_as_uint(f);
    unsigned r = (u + 0x7FFFu + ((u >> 16) & 1u)) >> 16;
    return (unsigned short)r;
}
static __device__ __forceinline__ float bf2f(unsigned short h) {
    return __uint_as_float(((unsigned)h) << 16);
}

// ---------------- merged prep: et, cnorm, fragments, zero loss+counter ----------------
// grid 8 x 512. tid 0..4095.
__global__ __launch_bounds__(512) void vq_prep(const float* __restrict__ emb,
                                               float* __restrict__ wsf) {
    const int tid = blockIdx.x * 512 + threadIdx.x;   // 0..4095

    // ---- part B: et (code-major) + cnorm, 8 threads per code ----
    {
        int k  = tid >> 3;            // 0..511
        int d0 = (tid & 7) * 8;
        float s = 0.f;
        float* et = wsf + WS_ET;
        #pragma unroll
        for (int i = 0; i < 8; ++i) {
            float e = emb[(d0 + i) * KCB + k];
            s += e * e;
            et[k * DDIM + d0 + i] = e;
        }
        s += __shfl_xor(s, 1);
        s += __shfl_xor(s, 2);
        s += __shfl_xor(s, 4);
        if ((tid & 7) == 0) wsf[WS_CNORM + k] = s;
        if (tid == 0) {
            wsf[WS_LOSS] = 0.f;
            ((unsigned*)wsf)[WS_DONE] = 0u;
        }
    }

    // ---- part A: codebook MFMA A-fragments (hi/lo bf16) ----
    // frag index ((t*2+c)*64 + lane): 8 bf16 = A[m=t*16+(lane&15)][k=c*32+quad*8+j]
    {
        int l = tid & 63;
        int c = (tid >> 6) & 1;
        int t = tid >> 7;
        int m = t * 16 + (l & 15);
        int dbase = c * 32 + ((l >> 4) & 3) * 8;
        unsigned hh[4], ll[4];
        #pragma unroll
        for (int j2 = 0; j2 < 4; ++j2) {
            float f0 = emb[(dbase + 2 * j2 + 0) * KCB + m];
            float f1 = emb[(dbase + 2 * j2 + 1) * KCB + m];
            unsigned short h0 = f2bf_rne(f0), h1 = f2bf_rne(f1);
            unsigned short l0 = f2bf_rne(f0 - bf2f(h0)), l1 = f2bf_rne(f1 - bf2f(h1));
            hh[j2] = (unsigned)h0 | ((unsigned)h1 << 16);
            ll[j2] = (unsigned)l0 | ((unsigned)l1 << 16);
        }
        uint4* ehp = (uint4*)(wsf + WS_EH);
        uint4* elp = (uint4*)(wsf + WS_EL);
        ehp[tid] = make_uint4(hh[0], hh[1], hh[2], hh[3]);
        elp[tid] = make_uint4(ll[0], ll[1], ll[2], ll[3]);
    }
}

// ---------------- main: 1024-thr block = 16 waves, both tables in LDS, 2 passes ----------------
// Each wave handles 32 vectors/pass vs all 512 codes; 2 passes/block.
// LDS: eh 64KB + el 64KB + cn 2KB = 130KB -> 1 block/CU, 16 waves resident.
// __launch_bounds__(1024, 4): min 4 waves/EU (which LDS forces anyway) ->
// VGPR cap 128; j=2 live set ~105 fits -> no spill, prefetch survives.
__global__ __launch_bounds__(1024, 4) void vq_main_mfma(const float* __restrict__ x,
                                                        float* __restrict__ wsf,
                                                        float* __restrict__ out) {
    const int lane = threadIdx.x & 63;
    const int quad = lane >> 4;
    const int wid  = threadIdx.x >> 6;

    __shared__ uint4  sh_eh[32 * 2 * 64];   // 64 KB
    __shared__ uint4  sh_el[32 * 2 * 64];   // 64 KB
    __shared__ float4 sh_cn[128];           // 2 KB: -0.5 * ||e||^2
    __shared__ float  redls[16];

    // ---- stage codebook fragments + scaled norms into LDS (once per block) ----
    {
        const uint4* geh = (const uint4*)(wsf + WS_EH);
        const uint4* gel = (const uint4*)(wsf + WS_EL);
        const int tid = threadIdx.x;
        #pragma unroll
        for (int i = 0; i < 4; ++i) {
            sh_eh[tid + i * 1024] = geh[tid + i * 1024];
            sh_el[tid + i * 1024] = gel[tid + i * 1024];
        }
        if (tid < 128) {
            float4 c = ((const float4*)(wsf + WS_CNORM))[tid];
            sh_cn[tid] = make_float4(-0.5f * c.x, -0.5f * c.y,
                                     -0.5f * c.z, -0.5f * c.w);
        }
    }

    const float* __restrict__ et = wsf + WS_ET;
    float* __restrict__ loss_accum = wsf + WS_LOSS;

    float loss_ws = 0.f;

    #pragma unroll 1
    for (int pass = 0; pass < 2; ++pass) {
        const int nbase = (blockIdx.x * 2 + pass) * 512 + wid * 32;

        // ---- load 32 x rows, build B-fragments (hi/lo), accumulate ||x||^2 ----
        bf16x8 xh[2][2], xl[2][2];
        float xnorm[2];
        #pragma unroll
        for (int j = 0; j < 2; ++j) {
            float s = 0.f;
            #pragma unroll
            for (int c = 0; c < 2; ++c) {
                const float* xrow = x + (size_t)(nbase + j * 16 + (lane & 15)) * DDIM
                                      + c * 32 + quad * 8;
                float4 xa = *(const float4*)xrow;
                float4 xb = *(const float4*)(xrow + 4);
                s += xa.x * xa.x + xa.y * xa.y + xa.z * xa.z + xa.w * xa.w;
                s += xb.x * xb.x + xb.y * xb.y + xb.z * xb.z + xb.w * xb.w;
                float f[8] = {xa.x, xa.y, xa.z, xa.w, xb.x, xb.y, xb.z, xb.w};
                union { bf16x8 v; unsigned short u[8]; } H, L;
                #pragma unroll
                for (int e = 0; e < 8; ++e) {
                    unsigned short h = f2bf_rne(f[e]);
                    H.u[e] = h;
                    L.u[e] = f2bf_rne(f[e] - bf2f(h));
                }
                xh[j][c] = H.v;
                xl[j][c] = L.v;
            }
            // sum partial ||x||^2 across the 4 quads (bits 4,5 of lane)
            s += __shfl_xor(s, 16);
            s += __shfl_xor(s, 32);
            xnorm[j] = s;
        }

        __syncthreads();

        const bf16x8* __restrict__ ehv = (const bf16x8*)sh_eh;
        const bf16x8* __restrict__ elv = (const bf16x8*)sh_el;

        // ---- argmax of score = sim - 0.5*||e||^2 over 32 code-tiles ----
        float best[2], second[2];
        int bestv[2];  // t*16 + reg  (full code = bestv + quad*4)
        #pragma unroll
        for (int j = 0; j < 2; ++j) { best[j] = -3.4e38f; second[j] = -3.4e38f; bestv[j] = 0; }

        // prefetched fragments for tile t
        bf16x8 eh0 = ehv[lane], eh1 = ehv[64 + lane];
        bf16x8 el0 = elv[lane], el1 = elv[64 + lane];

        #pragma unroll 1
        for (int t = 0; t < 32; ++t) {
            // prefetch t+1 (wraps to t=0 on last iter; harmless, unused)
            const int tn = (t + 1) & 31;
            bf16x8 neh0 = ehv[(tn * 2 + 0) * 64 + lane];
            bf16x8 neh1 = ehv[(tn * 2 + 1) * 64 + lane];
            bf16x8 nel0 = elv[(tn * 2 + 0) * 64 + lane];
            bf16x8 nel1 = elv[(tn * 2 + 1) * 64 + lane];
            float4 cn = sh_cn[t * 4 + quad];
            const int kb = t * 16;
            #pragma unroll
            for (int j = 0; j < 2; ++j) {
                f32x4 acc = {cn.x, cn.y, cn.z, cn.w};   // start at -0.5*||e||^2
                acc = __builtin_amdgcn_mfma_f32_16x16x32_bf16(eh0, xh[j][0], acc, 0, 0, 0);
                acc = __builtin_amdgcn_mfma_f32_16x16x32_bf16(eh1, xh[j][1], acc, 0, 0, 0);
                acc = __builtin_amdgcn_mfma_f32_16x16x32_bf16(el0, xh[j][0], acc, 0, 0, 0);
                acc = __builtin_amdgcn_mfma_f32_16x16x32_bf16(el1, xh[j][1], acc, 0, 0, 0);
                acc = __builtin_amdgcn_mfma_f32_16x16x32_bf16(eh0, xl[j][0], acc, 0, 0, 0);
                acc = __builtin_amdgcn_mfma_f32_16x16x32_bf16(eh1, xl[j][1], acc, 0, 0, 0);
                #pragma unroll
                for (int r = 0; r < 4; ++r) {
                    float s = acc[r];
                    // new second = median(s, best, second) given best >= second
                    second[j] = __builtin_amdgcn_fmed3f(s, best[j], second[j]);
                    bool gt = s > best[j];
                    bestv[j] = gt ? (kb + r) : bestv[j];
                    best[j] = fmaxf(best[j], s);
                }
            }
            eh0 = neh0; eh1 = neh1; el0 = nel0; el1 = nel1;
        }

        // ---- reduce across the 4 quads (lanes n, n+16, n+32, n+48) ----
        int bk[2];
        #pragma unroll
        for (int j = 0; j < 2; ++j) bk[j] = bestv[j] + quad * 4;
        #pragma unroll
        for (int j = 0; j < 2; ++j) {
            #pragma unroll
            for (int m = 16; m <= 32; m <<= 1) {
                float ob = __shfl_xor(best[j], m);
                float os = __shfl_xor(second[j], m);
                int   ok = __shfl_xor(bk[j], m);
                float nb = fmaxf(best[j], ob);
                float ns = fmaxf(fmaxf(second[j], os), fminf(best[j], ob));
                bool take = (ob > best[j]) || (ob == best[j] && ok < bk[j]);
                bk[j] = take ? ok : bk[j];
                best[j] = nb;
                second[j] = ns;
            }
        }

        // ---- back to distance domain: dist = -2*score  (||x||^2 dropped) ----
        float bd[2], sd[2];
        #pragma unroll
        for (int j = 0; j < 2; ++j) { bd[j] = -2.f * best[j]; sd[j] = -2.f * second[j]; }

        // ---- near-tie: whole-wave cooperative exact fp64 rescan (rare) ----
        #pragma unroll
        for (int j = 0; j < 2; ++j) {
            unsigned long long need = __ballot(sd[j] - bd[j] < TIE_TH) & 0xFFFFULL;
            while (need) {
                int nl = __ffsll(need) - 1;
                need &= need - 1;
                const float* xr = x + (size_t)(nbase + j * 16 + nl) * DDIM;
                double dmin = 1e300;
                int kmin = 0;
                #pragma unroll
                for (int i = 0; i < 8; ++i) {
                    int k = lane * 8 + i;
                    const float* er = et + k * DDIM;
                    double s = 0.0;
                    for (int d4 = 0; d4 < 16; ++d4) {
                        float4 xv = *(const float4*)(xr + d4 * 4);
                        float4 ev = *(const float4*)(er + d4 * 4);
                        double a = (double)xv.x - (double)ev.x; s += a * a;
                        double b = (double)xv.y - (double)ev.y; s += b * b;
                        double c = (double)xv.z - (double)ev.z; s += c * c;
                        double e = (double)xv.w - (double)ev.w; s += e * e;
                    }
                    if (s < dmin) { dmin = s; kmin = k; }
                }
                #pragma unroll
                for (int m = 1; m < 64; m <<= 1) {
                    double od = __shfl_xor(dmin, m);
                    int   ok = __shfl_xor(kmin, m);
                    if (od < dmin || (od == dmin && ok < kmin)) { dmin = od; kmin = ok; }
                }
                if ((lane & 15) == nl) {
                    bk[j] = kmin;
                    bd[j] = (float)dmin - xnorm[j];  // keep loss exact
                }
            }
        }

        // ---- loss partial: sum (q-x)^2 = xnorm + bd over this wave's 32 n ----
        float ls = 0.f;
        if (lane < 16) {
            #pragma unroll
            for (int j = 0; j < 2; ++j) ls += fmaxf(xnorm[j] + bd[j], 0.f);
        }
        #pragma unroll
        for (int m = 1; m < 64; m <<= 1) ls += __shfl_xor(ls, m);
        loss_ws += ls;

        // ---- write quantized rows: lane -> (n = lane>>2, 64B slice = lane&3) ----
        #pragma unroll
        for (int j = 0; j < 2; ++j) {
            int bkn = __shfl(bk[j], lane >> 2);
            const float4* er = (const float4*)(et + (size_t)bkn * DDIM + (lane & 3) * 16);
            float4* op = (float4*)(out + (size_t)(nbase + j * 16 + (lane >> 2)) * DDIM
                                       + (lane & 3) * 16);
            op[0] = er[0]; op[1] = er[1]; op[2] = er[2]; op[3] = er[3];
        }
    }

    // ---- fused final: block loss reduce + done-counter, last block writes ----
    if (lane == 0) redls[wid] = loss_ws;
    __syncthreads();
    if (threadIdx.x == 0) {
        float Lb = 0.f;
        #pragma unroll
        for (int i = 0; i < 16; ++i) Lb += redls[i];
        atomicAdd(loss_accum, Lb);
        __threadfence();
        unsigned d = atomicAdd((unsigned*)wsf + WS_DONE, 1u);
        if (d == gridDim.x - 1) {
            float L = atomicAdd(loss_accum, 0.f);   // coherent read-back
            out[(size_t)NVEC * DDIM] = 1.25f * L / 16777216.f;
        }
    }
}

// ---------------- legacy fallback path (ws too small for fragment tables) ----------------
__global__ __launch_bounds__(512) void vq_prep1(const float* __restrict__ emb,
                                                float* __restrict__ wsf) {
    int k = threadIdx.x;
    float s = 0.f;
    float* et = wsf + WS_ET;
    #pragma unroll
    for (int d = 0; d < DDIM; ++d) {
        float e = emb[d * KCB + k];
        s += e * e;
        et[k * DDIM + d] = e;
    }
    wsf[WS_CNORM + k] = s;
    if (k == 0) wsf[WS_LOSS] = 0.f;
}

__global__ __launch_bounds__(256) void vq_main_legacy(const float* __restrict__ x,
                                                      const float* __restrict__ emb,
                                                      const float* __restrict__ wsf,
                                                      float* __restrict__ out,
                                                      float* __restrict__ loss_accum) {
    const int n = blockIdx.x * 256 + threadIdx.x;
    const float* __restrict__ cnorm = wsf + WS_CNORM;
    const float* __restrict__ et    = wsf + WS_ET;
    float xr[DDIM];
    {
        const float4* xp = (const float4*)(x + (size_t)n * DDIM);
        #pragma unroll
        for (int d4 = 0; d4 < DDIM / 4; ++d4) {
            float4 v = xp[d4];
            xr[4 * d4 + 0] = v.x; xr[4 * d4 + 1] = v.y;
            xr[4 * d4 + 2] = v.z; xr[4 * d4 + 3] = v.w;
        }
    }
    float best = 3.4e38f, second = 3.4e38f;
    int bestk = 0;
    for (int k0 = 0; k0 < KCB; k0 += 8) {
        float acc[8];
        #pragma unroll
        for (int j = 0; j < 8; ++j) {
            const float* ek = et + (k0 + j) * DDIM;
            float s = 0.f;
            #pragma unroll
            for (int d = 0; d < DDIM; ++d) s += xr[d] * ek[d];
            acc[j] = s;
        }
        #pragma unroll
        for (int j = 0; j < 8; ++j) {
            float dist = cnorm[k0 + j] - 2.f * acc[j];
            if (dist < best) { second = best; best = dist; bestk = k0 + j; }
            else if (dist < second) { second = dist; }
        }
    }
    if (second - best < TIE_TH) {
        double bestd = 1e300;
        int bkk = 0;
        for (int k = 0; k < KCB; ++k) {
            const float* ek = et + k * DDIM;
            double s = 0.0;
            #pragma unroll
            for (int d = 0; d < DDIM; ++d) {
                double diff = (double)xr[d] - (double)ek[d];
                s += diff * diff;
            }
            if (s < bestd) { bestd = s; bkk = k; }
        }
        bestk = bkk;
    }
    float sq = 0.f;
    {
        const float4* qp = (const float4*)(et + bestk * DDIM);
        float4* op = (float4*)(out + (size_t)n * DDIM);
        #pragma unroll
        for (int d4 = 0; d4 < DDIM / 4; ++d4) {
            float4 q = qp[d4];
            op[d4] = q;
            float a = q.x - xr[4 * d4 + 0];
            float b = q.y - xr[4 * d4 + 1];
            float c = q.z - xr[4 * d4 + 2];
            float e = q.w - xr[4 * d4 + 3];
            sq += a * a + b * b + c * c + e * e;
        }
    }
    #pragma unroll
    for (int off = 32; off > 0; off >>= 1) sq += __shfl_down(sq, off);
    __shared__ float red[4];
    const int lane = threadIdx.x & 63;
    const int wid  = threadIdx.x >> 6;
    if (lane == 0) red[wid] = sq;
    __syncthreads();
    if (threadIdx.x == 0) atomicAdd(loss_accum, red[0] + red[1] + red[2] + red[3]);
}

__global__ void vq_final(const float* __restrict__ loss_accum,
                         float* __restrict__ out) {
    out[(size_t)NVEC * DDIM] = 1.25f * loss_accum[0] / 16777216.f;
}

extern "C" void kernel_launch(void* const* d_in, const int* in_sizes, int n_in,
                              void* d_out, int out_size, void* d_ws, size_t ws_size,
                              hipStream_t stream) {
    const float* x   = (const float*)d_in[0];
    const float* emb = (const float*)d_in[1];
    float* out = (float*)d_out;
    float* wsf = (float*)d_ws;

    if (ws_size >= (size_t)WS_END * 4) {
        vq_prep<<<8, 512, 0, stream>>>(emb, wsf);
        vq_main_mfma<<<NVEC / 1024, 1024, 0, stream>>>(x, wsf, out);
        // loss written by last finishing block of vq_main_mfma
    } else {
        vq_prep1<<<1, 512, 0, stream>>>(emb, wsf);
        vq_main_legacy<<<NVEC / 256, 256, 0, stream>>>(x, emb, wsf, out, wsf + WS_LOSS);
        vq_final<<<1, 1, 0, stream>>>(wsf + WS_LOSS, out);
    }
}